// Round 9
// baseline (243.219 us; speedup 1.0000x reference)
//
#include <hip/hip_runtime.h>
#include <hip/hip_fp16.h>

#define IN_F   100000
#define OUT_F  100000
#define NNZ_N  1600000
#define TC     256
#define TBLK   ((IN_F + TC - 1) / TC)      // 391 transpose blocks
#define SBLK   ((NNZ_N + 255) / 256)       // 6250 scan blocks
#define RBLK   ((OUT_F + 63) / 64)         // 1563 spmm blocks
#define ED_CAP 2048                         // staged edges/block (mean 1024, sigma 32)

__device__ __forceinline__ float2 h2f(unsigned u) {
    const __half2 h = *reinterpret_cast<const __half2*>(&u);
    return __half22float2(h);
}

#define EDGE_FMA(U, V) do { float2 f_;                                         \
    f_ = h2f((U).x); acc[0] = fmaf((V), f_.x, acc[0]); acc[1] = fmaf((V), f_.y, acc[1]); \
    f_ = h2f((U).y); acc[2] = fmaf((V), f_.x, acc[2]); acc[3] = fmaf((V), f_.y, acc[3]); \
    f_ = h2f((U).z); acc[4] = fmaf((V), f_.x, acc[4]); acc[5] = fmaf((V), f_.y, acc[5]); \
    f_ = h2f((U).w); acc[6] = fmaf((V), f_.x, acc[6]); acc[7] = fmaf((V), f_.y, acc[7]); \
} while (0)

// ---------------------------------------------------------------------------
// Prep (fused, proven): blocks [0,TBLK) transpose x (64,IN) f32 -> xh (IN,64)
// f16 (u32 word: col*32 + p, pair p = batches 2p,2p+1). Blocks [TBLK,..) do
// the rowstart linear scan over sorted rows.
// ---------------------------------------------------------------------------
__global__ __launch_bounds__(256) void k_prep(
    const float* __restrict__ x,
    const int*   __restrict__ rows,
    unsigned* __restrict__ xh,
    int*      __restrict__ rstart) {
    __shared__ unsigned tile[TC][33];
    const int bid = blockIdx.x;
    const int t   = threadIdx.x;

    if (bid < TBLK) {
        const int i0   = bid * TC;
        const int colr = i0 + t;
        if (colr < IN_F) {
            #pragma unroll 8
            for (int p = 0; p < 32; ++p) {
                const float a = x[(size_t)(2 * p)     * IN_F + colr];
                const float b = x[(size_t)(2 * p + 1) * IN_F + colr];
                const __half2 h = __floats2half2_rn(a, b);
                tile[t][p] = *reinterpret_cast<const unsigned*>(&h);
            }
        }
        __syncthreads();
        const int u  = t & 31;              // batch pair
        const int c8 = t >> 5;
        for (int cc = c8; cc < TC; cc += 8) {
            const int col = i0 + cc;
            if (col < IN_F)
                xh[(size_t)col * 32 + u] = tile[cc][u];
        }
    } else {
        const int e = (bid - TBLK) * 256 + t;
        if (e >= NNZ_N) return;
        const int cur  = rows[e];
        const int prev = (e == 0) ? -1 : rows[e - 1];
        for (int r = prev + 1; r <= cur; ++r) rstart[r] = e;
        if (e == NNZ_N - 1)
            for (int r = cur + 1; r <= OUT_F; ++r) rstart[r] = NNZ_N;
    }
}

// ---------------------------------------------------------------------------
// SpMM: block = 512 threads = 8 waves = 64 rows; 8-lane group owns one row,
// lane sub in [0,8) covers batches 8sub..8sub+7 (uint4 = 8 halves = one
// 128B line per edge per group). Edge list staged coalesced into LDS
// (index reads = same-address LDS broadcasts). Unroll-8 -> 8 independent
// gather lines per lane, 64 per wave. fp32 register accumulate; direct tile
// write (no atomics); coalesced transpose epilogue.
// NOTE __launch_bounds__ 2nd arg is MIN WAVES PER SIMD (EU), not blocks/CU:
// 8 waves/EU = 32 waves/CU = 4 blocks/CU (LDS 33.8KB x4 = 135KB < 160KB;
// VGPR cap 64 >= the ~32 this kernel uses). The previous (512,4) silently
// capped residency at 2 blocks/CU -> occupancy 58-66% all session.
// ---------------------------------------------------------------------------
__global__ __launch_bounds__(512, 8) void k_spmm(
    const uint4* __restrict__ xh4,        // col*8 + sub
    const int*   __restrict__ rstart,
    const int*   __restrict__ cols,
    const float* __restrict__ vals,
    const float* __restrict__ bias,
    float* __restrict__ out) {
    __shared__ int   rs[65];
    __shared__ int   ecol[ED_CAP];
    __shared__ float eval[ED_CAP];
    __shared__ float tile[64][65];
    const int r0   = blockIdx.x * 64;
    const int t    = threadIdx.x;
    const int lane = t & 63;
    const int w    = t >> 6;

    if (t < 65) {
        int idx = r0 + t; if (idx > OUT_F) idx = OUT_F;
        rs[t] = rstart[idx];
    }
    __syncthreads();

    const int s  = rs[0];
    const int ne = rs[64] - s;
    const int ns = (ne < ED_CAP) ? ne : ED_CAP;
    for (int i = t; i < ns; i += 512) {
        ecol[i] = cols[s + i];
        eval[i] = vals[s + i];
    }
    __syncthreads();

    const int gg  = t >> 3;               // group -> local row 0..63
    const int sub = t & 7;                // batch octet
    const int ls  = rs[gg]     - s;       // local [ls, n) edge range
    const int n   = rs[gg + 1] - s;

    float acc[8];
    #pragma unroll
    for (int i = 0; i < 8; ++i) acc[i] = 0.f;

    if (ne <= ED_CAP) {
        for (int base = ls; base < n; base += 8) {
            int c[8]; float v[8];
            #pragma unroll
            for (int j = 0; j < 8; ++j) {
                const int i = (base + j < n) ? base + j : n - 1;
                c[j] = ecol[i];
                v[j] = (base + j < n) ? eval[i] : 0.f;
            }
            uint4 u[8];
            #pragma unroll
            for (int j = 0; j < 8; ++j)
                u[j] = xh4[(size_t)c[j] * 8 + sub];
            #pragma unroll
            for (int j = 0; j < 8; ++j)
                EDGE_FMA(u[j], v[j]);
        }
    } else {                               // ~32-sigma event; correctness only
        for (int base = ls; base < n; base += 8) {
            int c[8]; float v[8];
            #pragma unroll
            for (int j = 0; j < 8; ++j) {
                const int i = (base + j < n) ? base + j : n - 1;
                c[j] = cols[s + i];
                v[j] = (base + j < n) ? vals[s + i] : 0.f;
            }
            uint4 u[8];
            #pragma unroll
            for (int j = 0; j < 8; ++j)
                u[j] = xh4[(size_t)c[j] * 8 + sub];
            #pragma unroll
            for (int j = 0; j < 8; ++j)
                EDGE_FMA(u[j], v[j]);
        }
    }

    // tile[gg][8sub+i]: bank = (gg + 8sub + i) mod 32 -> 2 lanes/bank = free
    #pragma unroll
    for (int i = 0; i < 8; ++i) tile[gg][(sub << 3) + i] = acc[i];
    __syncthreads();

    const int rc = r0 + lane;
    if (rc < OUT_F) {
        const float bv = bias[rc];
        for (int bb = w; bb < 64; bb += 8)
            out[(size_t)bb * OUT_F + rc] = tile[lane][bb] + bv;
    }
}

// ---------------------------------------------------------------------------
// Fallback (insufficient ws): gather from native x layout. Correct, slow.
// ---------------------------------------------------------------------------
__global__ __launch_bounds__(256) void k_spmm_fallback(
    const float* __restrict__ x,
    const float* __restrict__ vals,
    const int*   __restrict__ rows,
    const int*   __restrict__ cols,
    const float* __restrict__ bias,
    float* __restrict__ out) {
    __shared__ int   rstart[65];
    __shared__ float tile[64][65];
    const int r0   = blockIdx.x * 64;
    const int t    = threadIdx.x;
    const int lane = t & 63;
    const int w    = t >> 6;
    if (t < 65) {
        const int target = r0 + t;
        int lo = 0, hi = NNZ_N;
        while (lo < hi) {
            const int mid = (lo + hi) >> 1;
            if (rows[mid] < target) lo = mid + 1; else hi = mid;
        }
        rstart[t] = lo;
    }
    __syncthreads();
    for (int j = w; j < 64; j += 4) {
        const int s = rstart[j], e = rstart[j + 1];
        float acc = 0.f;
        const size_t base = (size_t)lane * IN_F;
        for (int idx = s; idx < e; ++idx)
            acc = fmaf(vals[idx], x[base + cols[idx]], acc);
        tile[j][lane] = acc;
    }
    __syncthreads();
    const int c = lane;
    if (r0 + c < OUT_F) {
        const float bv = bias[r0 + c];
        for (int bb = w; bb < 64; bb += 4)
            out[(size_t)bb * OUT_F + (r0 + c)] = tile[c][bb] + bv;
    }
}

extern "C" void kernel_launch(void* const* d_in, const int* in_sizes, int n_in,
                              void* d_out, int out_size, void* d_ws, size_t ws_size,
                              hipStream_t stream) {
    const float* x      = (const float*)d_in[0];
    const float* values = (const float*)d_in[1];
    const float* bias   = (const float*)d_in[2];
    const int*   rows   = (const int*)d_in[3];
    const int*   cols   = (const int*)d_in[4];
    float*       out    = (float*)d_out;

    const size_t xh_bytes = (size_t)IN_F * 32 * sizeof(unsigned);   // 12.8 MB
    const size_t rs_off   = (xh_bytes + 255) & ~(size_t)255;
    const size_t need     = rs_off + (size_t)(OUT_F + 1) * sizeof(int); // ~13.2 MB

    if (ws_size >= need) {
        unsigned* xh     = (unsigned*)d_ws;
        int*      rstart = (int*)((char*)d_ws + rs_off);
        k_prep<<<TBLK + SBLK, 256, 0, stream>>>(x, rows, xh, rstart);
        k_spmm<<<RBLK, 512, 0, stream>>>((const uint4*)xh, rstart, cols, values, bias, out);
    } else {
        k_spmm_fallback<<<RBLK, 256, 0, stream>>>(x, values, rows, cols, bias, out);
    }
}

// Round 10
// 125.654 us; speedup vs baseline: 1.9356x; 1.9356x over previous
//
#include <hip/hip_runtime.h>
#include <hip/hip_fp16.h>

#define IN_F   100000
#define OUT_F  100000
#define NNZ_N  1600000
#define TC     256
#define TBLK   ((IN_F + TC - 1) / TC)      // 391 transpose blocks
#define SBLK   ((NNZ_N + 255) / 256)       // 6250 scan blocks
#define RBLK   ((OUT_F + 63) / 64)         // 1563 spmm blocks
#define ED_CAP 2048                         // staged edges/block (mean 1024, sigma 32)

__device__ __forceinline__ float2 h2f(unsigned u) {
    const __half2 h = *reinterpret_cast<const __half2*>(&u);
    return __half22float2(h);
}

#define EDGE_FMA(U, V) do { float2 f_;                                         \
    f_ = h2f((U).x); acc[0] = fmaf((V), f_.x, acc[0]); acc[1] = fmaf((V), f_.y, acc[1]); \
    f_ = h2f((U).y); acc[2] = fmaf((V), f_.x, acc[2]); acc[3] = fmaf((V), f_.y, acc[3]); \
    f_ = h2f((U).z); acc[4] = fmaf((V), f_.x, acc[4]); acc[5] = fmaf((V), f_.y, acc[5]); \
    f_ = h2f((U).w); acc[6] = fmaf((V), f_.x, acc[6]); acc[7] = fmaf((V), f_.y, acc[7]); \
} while (0)

// ---------------------------------------------------------------------------
// Prep (fused, proven): blocks [0,TBLK) transpose x (64,IN) f32 -> xh (IN,64)
// f16 (u32 word: col*32 + p, pair p = batches 2p,2p+1). Blocks [TBLK,..) do
// the rowstart linear scan over sorted rows.
// ---------------------------------------------------------------------------
__global__ __launch_bounds__(256) void k_prep(
    const float* __restrict__ x,
    const int*   __restrict__ rows,
    unsigned* __restrict__ xh,
    int*      __restrict__ rstart) {
    __shared__ unsigned tile[TC][33];
    const int bid = blockIdx.x;
    const int t   = threadIdx.x;

    if (bid < TBLK) {
        const int i0   = bid * TC;
        const int colr = i0 + t;
        if (colr < IN_F) {
            #pragma unroll 8
            for (int p = 0; p < 32; ++p) {
                const float a = x[(size_t)(2 * p)     * IN_F + colr];
                const float b = x[(size_t)(2 * p + 1) * IN_F + colr];
                const __half2 h = __floats2half2_rn(a, b);
                tile[t][p] = *reinterpret_cast<const unsigned*>(&h);
            }
        }
        __syncthreads();
        const int u  = t & 31;              // batch pair
        const int c8 = t >> 5;
        for (int cc = c8; cc < TC; cc += 8) {
            const int col = i0 + cc;
            if (col < IN_F)
                xh[(size_t)col * 32 + u] = tile[cc][u];
        }
    } else {
        const int e = (bid - TBLK) * 256 + t;
        if (e >= NNZ_N) return;
        const int cur  = rows[e];
        const int prev = (e == 0) ? -1 : rows[e - 1];
        for (int r = prev + 1; r <= cur; ++r) rstart[r] = e;
        if (e == NNZ_N - 1)
            for (int r = cur + 1; r <= OUT_F; ++r) rstart[r] = NNZ_N;
    }
}

// ---------------------------------------------------------------------------
// SpMM: block = 512 threads = 8 waves = 64 rows; 8-lane group owns one row,
// lane sub in [0,8) covers batches 8sub..8sub+7 (uint4 = 8 halves = one
// 128B line per edge per group). Edge list staged coalesced into LDS
// (index reads = same-address LDS broadcasts). Unroll-4: u[4]+c[4]+v[4]+acc
// fits the 64-VGPR cap that 8 waves/SIMD requires (round-4 codegen measured
// VGPR=32 for this loop) -> NO scratch spill, unlike unroll-8 which needs
// ~100 VGPR (round-9: 290 MB scratch WRITE_SIZE at the 64 cap).
// __launch_bounds__(512,8): 8 waves/EU = 32 waves/CU = 4 blocks/CU
// (LDS 33.8KB x4 = 135KB < 160KB). ILP(4 lines/lane) x TLP(2x waves) keeps
// aggregate in-flight lines equal to unroll-8 at 2 blocks/CU but hides
// latency via wave interleave instead of register-hungry deep unroll.
// ---------------------------------------------------------------------------
__global__ __launch_bounds__(512, 8) void k_spmm(
    const uint4* __restrict__ xh4,        // col*8 + sub
    const int*   __restrict__ rstart,
    const int*   __restrict__ cols,
    const float* __restrict__ vals,
    const float* __restrict__ bias,
    float* __restrict__ out) {
    __shared__ int   rs[65];
    __shared__ int   ecol[ED_CAP];
    __shared__ float eval[ED_CAP];
    __shared__ float tile[64][65];
    const int r0   = blockIdx.x * 64;
    const int t    = threadIdx.x;
    const int lane = t & 63;
    const int w    = t >> 6;

    if (t < 65) {
        int idx = r0 + t; if (idx > OUT_F) idx = OUT_F;
        rs[t] = rstart[idx];
    }
    __syncthreads();

    const int s  = rs[0];
    const int ne = rs[64] - s;
    const int ns = (ne < ED_CAP) ? ne : ED_CAP;
    for (int i = t; i < ns; i += 512) {
        ecol[i] = cols[s + i];
        eval[i] = vals[s + i];
    }
    __syncthreads();

    const int gg  = t >> 3;               // group -> local row 0..63
    const int sub = t & 7;                // batch octet
    const int ls  = rs[gg]     - s;       // local [ls, n) edge range
    const int n   = rs[gg + 1] - s;

    float acc[8];
    #pragma unroll
    for (int i = 0; i < 8; ++i) acc[i] = 0.f;

    if (ne <= ED_CAP) {
        for (int base = ls; base < n; base += 4) {
            int c[4]; float v[4];
            #pragma unroll
            for (int j = 0; j < 4; ++j) {
                const int i = (base + j < n) ? base + j : n - 1;
                c[j] = ecol[i];
                v[j] = (base + j < n) ? eval[i] : 0.f;
            }
            uint4 u[4];
            #pragma unroll
            for (int j = 0; j < 4; ++j)
                u[j] = xh4[(size_t)c[j] * 8 + sub];
            #pragma unroll
            for (int j = 0; j < 4; ++j)
                EDGE_FMA(u[j], v[j]);
        }
    } else {                               // ~32-sigma event; correctness only
        for (int base = ls; base < n; base += 4) {
            int c[4]; float v[4];
            #pragma unroll
            for (int j = 0; j < 4; ++j) {
                const int i = (base + j < n) ? base + j : n - 1;
                c[j] = cols[s + i];
                v[j] = (base + j < n) ? vals[s + i] : 0.f;
            }
            uint4 u[4];
            #pragma unroll
            for (int j = 0; j < 4; ++j)
                u[j] = xh4[(size_t)c[j] * 8 + sub];
            #pragma unroll
            for (int j = 0; j < 4; ++j)
                EDGE_FMA(u[j], v[j]);
        }
    }

    // tile[gg][8sub+i]: bank = (gg + 8sub + i) mod 32 -> 2 lanes/bank = free
    #pragma unroll
    for (int i = 0; i < 8; ++i) tile[gg][(sub << 3) + i] = acc[i];
    __syncthreads();

    const int rc = r0 + lane;
    if (rc < OUT_F) {
        const float bv = bias[rc];
        for (int bb = w; bb < 64; bb += 8)
            out[(size_t)bb * OUT_F + rc] = tile[lane][bb] + bv;
    }
}

// ---------------------------------------------------------------------------
// Fallback (insufficient ws): gather from native x layout. Correct, slow.
// ---------------------------------------------------------------------------
__global__ __launch_bounds__(256) void k_spmm_fallback(
    const float* __restrict__ x,
    const float* __restrict__ vals,
    const int*   __restrict__ rows,
    const int*   __restrict__ cols,
    const float* __restrict__ bias,
    float* __restrict__ out) {
    __shared__ int   rstart[65];
    __shared__ float tile[64][65];
    const int r0   = blockIdx.x * 64;
    const int t    = threadIdx.x;
    const int lane = t & 63;
    const int w    = t >> 6;
    if (t < 65) {
        const int target = r0 + t;
        int lo = 0, hi = NNZ_N;
        while (lo < hi) {
            const int mid = (lo + hi) >> 1;
            if (rows[mid] < target) lo = mid + 1; else hi = mid;
        }
        rstart[t] = lo;
    }
    __syncthreads();
    for (int j = w; j < 64; j += 4) {
        const int s = rstart[j], e = rstart[j + 1];
        float acc = 0.f;
        const size_t base = (size_t)lane * IN_F;
        for (int idx = s; idx < e; ++idx)
            acc = fmaf(vals[idx], x[base + cols[idx]], acc);
        tile[j][lane] = acc;
    }
    __syncthreads();
    const int c = lane;
    if (r0 + c < OUT_F) {
        const float bv = bias[r0 + c];
        for (int bb = w; bb < 64; bb += 4)
            out[(size_t)bb * OUT_F + (r0 + c)] = tile[c][bb] + bv;
    }
}

extern "C" void kernel_launch(void* const* d_in, const int* in_sizes, int n_in,
                              void* d_out, int out_size, void* d_ws, size_t ws_size,
                              hipStream_t stream) {
    const float* x      = (const float*)d_in[0];
    const float* values = (const float*)d_in[1];
    const float* bias   = (const float*)d_in[2];
    const int*   rows   = (const int*)d_in[3];
    const int*   cols   = (const int*)d_in[4];
    float*       out    = (float*)d_out;

    const size_t xh_bytes = (size_t)IN_F * 32 * sizeof(unsigned);   // 12.8 MB
    const size_t rs_off   = (xh_bytes + 255) & ~(size_t)255;
    const size_t need     = rs_off + (size_t)(OUT_F + 1) * sizeof(int); // ~13.2 MB

    if (ws_size >= need) {
        unsigned* xh     = (unsigned*)d_ws;
        int*      rstart = (int*)((char*)d_ws + rs_off);
        k_prep<<<TBLK + SBLK, 256, 0, stream>>>(x, rows, xh, rstart);
        k_spmm<<<RBLK, 512, 0, stream>>>((const uint4*)xh, rstart, cols, values, bias, out);
    } else {
        k_spmm_fallback<<<RBLK, 256, 0, stream>>>(x, values, rows, cols, bias, out);
    }
}